// Round 4
// baseline (320.649 us; speedup 1.0000x reference)
//
#include <hip/hip_runtime.h>
#include <hip/hip_bf16.h>
#include <cstdint>
#include <cstddef>

// Problem constants
#define NT 8192
#define DD 512
#define HH 2048
#define NE 4
#define BK 64          // K-tile (bf16 elems); 8 chunks of 16B per row
#define RP 136         // repack LDS stride (elems) — breaks bank alignment
#define SMEM_ELEMS 17408  // max(staging 2*128*64=16384, repack 128*136=17408)

typedef short short8 __attribute__((ext_vector_type(8)));
typedef float floatx4 __attribute__((ext_vector_type(4)));

static __device__ __forceinline__ unsigned short f2bf(float f) {
    union { float f; uint32_t u; } v; v.f = f;
    uint32_t u = v.u;
    u += 0x7FFFu + ((u >> 16) & 1u);   // round-to-nearest-even
    return (unsigned short)(u >> 16);
}
static __device__ __forceinline__ float bf2f(unsigned short u) {
    union { uint32_t u; float f; } v; v.u = ((uint32_t)u) << 16; return v.f;
}

// async global->LDS, 16B per lane. LDS dest = wave-uniform base + lane*16.
static __device__ __forceinline__ void gld_lds16(const unsigned short* g, unsigned short* l) {
    __builtin_amdgcn_global_load_lds(
        (const __attribute__((address_space(1))) void*)g,
        (__attribute__((address_space(3))) void*)l, 16, 0, 0);
}

// ------------- merged batched transpose + cast (w1 and w2 in one launch) -------------
__global__ void k_transpose_cast(const float* __restrict__ w1, unsigned short* __restrict__ w1t,
                                 const float* __restrict__ w2, unsigned short* __restrict__ w2t) {
    int z = blockIdx.z;
    const float* in; unsigned short* out; int R, C, r0, c0;
    if (z < 4) {
        in = w1 + (size_t)z * DD * HH; out = w1t + (size_t)z * DD * HH;
        R = DD; C = HH; r0 = blockIdx.y * 32; c0 = blockIdx.x * 32;
    } else {
        in = w2 + (size_t)(z - 4) * HH * DD; out = w2t + (size_t)(z - 4) * HH * DD;
        R = HH; C = DD; r0 = blockIdx.x * 32; c0 = blockIdx.y * 32;
    }
    __shared__ float tile[32][33];
    int tx = threadIdx.x & 31, ty = threadIdx.x >> 5;
#pragma unroll
    for (int it = 0; it < 4; it++) {
        int r = ty + it * 8;
        tile[r][tx] = in[(size_t)(r0 + r) * C + c0 + tx];
    }
    __syncthreads();
#pragma unroll
    for (int it = 0; it < 4; it++) {
        int r = ty + it * 8;
        out[(size_t)(c0 + r) * R + r0 + tx] = f2bf(tile[tx][r]);
    }
}

// ------- gating (fp32 logits, exact top-2, softmax over top-2) + fused h->bf16 cast -------
__global__ void k_gate(const float* __restrict__ h, const float* __restrict__ wg,
                       int* __restrict__ sel, float* __restrict__ gv,
                       unsigned short* __restrict__ hb) {
    int wid = threadIdx.x >> 6, lane = threadIdx.x & 63;
    int n = blockIdx.x * 4 + wid;
    const float* hr = h + (size_t)n * DD;
    int d0 = lane * 8;
    float hv[8];
    *(float4*)(hv)     = *(const float4*)(hr + d0);
    *(float4*)(hv + 4) = *(const float4*)(hr + d0 + 4);
    unsigned short tmp[8];
#pragma unroll
    for (int j = 0; j < 8; j++) tmp[j] = f2bf(hv[j]);
    *(uint4*)(hb + (size_t)n * DD + d0) = *(const uint4*)tmp;

    float a0 = 0.f, a1 = 0.f, a2 = 0.f, a3 = 0.f;
#pragma unroll
    for (int j = 0; j < 8; j++) {
        float4 w = *(const float4*)(wg + (size_t)(d0 + j) * 4);
        a0 += hv[j] * w.x; a1 += hv[j] * w.y; a2 += hv[j] * w.z; a3 += hv[j] * w.w;
    }
#pragma unroll
    for (int off = 32; off; off >>= 1) {
        a0 += __shfl_xor(a0, off);
        a1 += __shfl_xor(a1, off);
        a2 += __shfl_xor(a2, off);
        a3 += __shfl_xor(a3, off);
    }
    if (lane == 0) {
        float v[4] = {a0, a1, a2, a3};
        int e0 = 0; float b = v[0];
#pragma unroll
        for (int e = 1; e < 4; e++) if (v[e] > b) { b = v[e]; e0 = e; }
        int e1 = -1; float b2 = -1e30f;
#pragma unroll
        for (int e = 0; e < 4; e++) if (e != e0 && v[e] > b2) { b2 = v[e]; e1 = e; }
        float x = expf(b2 - b);
        float s = 1.f + x;
        sel[2 * n] = e0; sel[2 * n + 1] = e1;
        gv[2 * n] = 1.f / s; gv[2 * n + 1] = x / s;
    }
}

// ---------------- single-block scan (1024 thr): counts -> offsets -> deterministic slots ----------------
// ctl: [8..11]=expert base, [12]=total
__global__ __launch_bounds__(1024) void k_scan(const int* __restrict__ sel, const float* __restrict__ gv,
                                               int* __restrict__ ctl, int* __restrict__ rtok,
                                               float* __restrict__ rgte, int* __restrict__ slotof) {
    __shared__ int cnt[4][1024];
    __shared__ int ebase[4];
    int t = threadIdx.x;
    int c[4] = {0, 0, 0, 0};
    int selloc[16];
    const int4* s4 = (const int4*)sel;
#pragma unroll
    for (int i = 0; i < 4; i++) {
        int4 v = s4[t * 4 + i];
        selloc[i * 4 + 0] = v.x; c[v.x]++;
        selloc[i * 4 + 1] = v.y; c[v.y]++;
        selloc[i * 4 + 2] = v.z; c[v.z]++;
        selloc[i * 4 + 3] = v.w; c[v.w]++;
    }
#pragma unroll
    for (int e = 0; e < 4; e++) cnt[e][t] = c[e];
    __syncthreads();
    for (int step = 1; step < 1024; step <<= 1) {
        int v[4];
#pragma unroll
        for (int e = 0; e < 4; e++) v[e] = (t >= step) ? cnt[e][t - step] : 0;
        __syncthreads();
#pragma unroll
        for (int e = 0; e < 4; e++) cnt[e][t] += v[e];
        __syncthreads();
    }
    if (t == 0) {
        int o = 0;
#pragma unroll
        for (int e = 0; e < 4; e++) { ebase[e] = o; ctl[8 + e] = o; o += cnt[e][1023]; }
        ctl[12] = o;
    }
    __syncthreads();
    int pos[4];
#pragma unroll
    for (int e = 0; e < 4; e++) pos[e] = ebase[e] + cnt[e][t] - c[e];  // exclusive prefix
#pragma unroll
    for (int i = 0; i < 16; i++) {
        int idx = t * 16 + i;          // = 2*n + k
        int e = selloc[i];
        int s = pos[e]++;
        rtok[s] = idx >> 1;
        rgte[s] = gv[idx];
        slotof[idx] = s;
    }
}

// ---------------- grouped GEMM 1: mid = relu(gather(h) @ w1[e] + b1[e]) ----------------
__global__ __launch_bounds__(256) void k_ffn1(
    const unsigned short* __restrict__ hb, const unsigned short* __restrict__ w1t,
    const float* __restrict__ b1, const int* __restrict__ ctl,
    const int* __restrict__ rtok, unsigned short* __restrict__ mid) {
    int e = blockIdx.z;
    // XCD swizzle: all 16 n-tiles of one m-tile land on the same XCD (flat%8 heuristic)
    int hid2 = blockIdx.x + 16 * blockIdx.y;   // [0,1024)
    int xcd = hid2 & 7, j2 = hid2 >> 3;        // j2 in [0,128)
    int mt = xcd * 8 + (j2 >> 4);              // [0,64)
    int n0 = (j2 & 15) * 128;
    int base = ctl[8 + e];
    int cnt = ctl[9 + e] - base;
    int m0 = mt * 128;
    if (m0 >= cnt) return;

    __shared__ unsigned short smem[SMEM_ELEMS];
    __shared__ int toks[128];
    unsigned short* As = smem;          // [128][64], swizzled chunks
    unsigned short* Bs = smem + 8192;

    int t = threadIdx.x;
    if (t < 128) {
        int r = m0 + t; if (r >= cnt) r = cnt - 1;
        toks[t] = rtok[base + r];
    }
    __syncthreads();

    const unsigned short* wB = w1t + (size_t)e * HH * DD;
    int wid = t >> 6, lane = t & 63;
    int wm = (wid & 1) * 64, wn = (wid >> 1) * 64;
    int lrow = lane & 15, quad = lane >> 4;

    // staging: wave stages 8 rows (128B each) per call, 4 calls per matrix.
    // swizzle: LDS slot (row, p) holds global chunk (p - row) & 7.
    const unsigned short* gA[4]; const unsigned short* gB[4];
    unsigned short* lA[4]; unsigned short* lB[4];
    int srow8 = lane >> 3, sch = lane & 7;
#pragma unroll
    for (int c = 0; c < 4; c++) {
        int row = wid * 32 + c * 8 + srow8;
        int cg = (sch - row) & 7;
        gA[c] = hb + (size_t)toks[row] * DD + cg * 8;
        gB[c] = wB + (size_t)(n0 + row) * DD + cg * 8;
        lA[c] = As + row * BK + sch * 8;
        lB[c] = Bs + row * BK + sch * 8;
    }

    floatx4 acc[4][4];
#pragma unroll
    for (int i = 0; i < 4; i++)
#pragma unroll
        for (int j = 0; j < 4; j++) acc[i][j] = (floatx4)0.f;

    for (int kk = 0; kk < DD; kk += BK) {
#pragma unroll
        for (int c = 0; c < 4; c++) {
            gld_lds16(gA[c] + kk, lA[c]);
            gld_lds16(gB[c] + kk, lB[c]);
        }
        __syncthreads();
#pragma unroll
        for (int ks = 0; ks < 2; ks++) {
            short8 af[4], bf[4];
#pragma unroll
            for (int i = 0; i < 4; i++) {
                int row = wm + 16 * i + lrow;
                af[i] = *(const short8*)&As[row * BK + (((ks << 2) + quad + row) & 7) * 8];
            }
#pragma unroll
            for (int j = 0; j < 4; j++) {
                int row = wn + 16 * j + lrow;
                bf[j] = *(const short8*)&Bs[row * BK + (((ks << 2) + quad + row) & 7) * 8];
            }
#pragma unroll
            for (int i = 0; i < 4; i++)
#pragma unroll
                for (int j = 0; j < 4; j++)
                    acc[i][j] = __builtin_amdgcn_mfma_f32_16x16x32_bf16(af[i], bf[j], acc[i][j], 0, 0, 0);
        }
        __syncthreads();
    }

    // epilogue: bias + relu -> LDS repack -> coalesced dwordx4 stores
#pragma unroll
    for (int j = 0; j < 4; j++) {
        int col = wn + 16 * j + lrow;
        float bias = b1[e * HH + n0 + col];
#pragma unroll
        for (int i = 0; i < 4; i++) {
#pragma unroll
            for (int r = 0; r < 4; r++) {
                int m = wm + 16 * i + quad * 4 + r;
                float v = acc[i][j][r] + bias;
                v = v > 0.f ? v : 0.f;
                smem[m * RP + col] = f2bf(v);
            }
        }
    }
    __syncthreads();
    {
        int row = t >> 1, half = t & 1;
        if (m0 + row < cnt) {
            unsigned short* dst = mid + (size_t)(base + m0 + row) * HH + n0 + half * 64;
            const unsigned short* src = smem + row * RP + half * 64;
#pragma unroll
            for (int it = 0; it < 8; it++)
                *(uint4*)(dst + it * 8) = *(const uint4*)(src + it * 8);
        }
    }
}

// ---------------- grouped GEMM 2 (512 thr, 8 waves): ybuf[slot] = gate * (mid @ w2[e] + b2[e]) ----------------
__global__ __launch_bounds__(512) void k_ffn2(
    const unsigned short* __restrict__ mid, const unsigned short* __restrict__ w2t,
    const float* __restrict__ b2, const int* __restrict__ ctl,
    const float* __restrict__ rgte, unsigned short* __restrict__ ybuf) {
    int e = blockIdx.z;
    // XCD swizzle: all 4 n-tiles of one m-tile on the same XCD
    int hid2 = blockIdx.x + 4 * blockIdx.y;    // [0,256)
    int xcd = hid2 & 7, j2 = hid2 >> 3;        // j2 in [0,32)
    int mt = xcd * 8 + (j2 >> 2);              // [0,64)
    int n0 = (j2 & 3) * 128;
    int base = ctl[8 + e];
    int cnt = ctl[9 + e] - base;
    int m0 = mt * 128;
    if (m0 >= cnt) return;

    __shared__ unsigned short smem[SMEM_ELEMS];
    __shared__ float gts[128];
    unsigned short* As = smem;
    unsigned short* Bs = smem + 8192;

    int t = threadIdx.x;
    if (t < 128) {
        int r = m0 + t; if (r >= cnt) r = cnt - 1;
        gts[t] = rgte[base + r];
    }
    __syncthreads();

    const unsigned short* wB = w2t + (size_t)e * DD * HH;
    int w = t >> 6, lane = t & 63;
    // wave tile: 32 (m) x 64 (n); 4x2 wave grid covers 128x128
    int wm = (w & 3) * 32, wn = (w >> 2) * 64;
    int lrow = lane & 15, quad = lane >> 4;

    // staging: waves 0-3 stage A (128 rows), waves 4-7 stage B (128 rows); 4 calls each
    const unsigned short* g[4]; unsigned short* l[4];
    int srow8 = lane >> 3, sch = lane & 7;
    int wrow0 = (w & 3) * 32;
    bool isA = w < 4;
#pragma unroll
    for (int c = 0; c < 4; c++) {
        int row = wrow0 + c * 8 + srow8;
        int cg = (sch - row) & 7;
        if (isA) {
            int ra = m0 + row; if (ra >= cnt) ra = cnt - 1;
            g[c] = mid + (size_t)(base + ra) * HH + cg * 8;
            l[c] = As + row * BK + sch * 8;
        } else {
            g[c] = wB + (size_t)(n0 + row) * HH + cg * 8;
            l[c] = Bs + row * BK + sch * 8;
        }
    }

    floatx4 acc[2][4];
#pragma unroll
    for (int i = 0; i < 2; i++)
#pragma unroll
        for (int j = 0; j < 4; j++) acc[i][j] = (floatx4)0.f;

    for (int kk = 0; kk < HH; kk += BK) {
#pragma unroll
        for (int c = 0; c < 4; c++) gld_lds16(g[c] + kk, l[c]);
        __syncthreads();
#pragma unroll
        for (int ks = 0; ks < 2; ks++) {
            short8 af[2], bf[4];
#pragma unroll
            for (int i = 0; i < 2; i++) {
                int row = wm + 16 * i + lrow;
                af[i] = *(const short8*)&As[row * BK + (((ks << 2) + quad + row) & 7) * 8];
            }
#pragma unroll
            for (int j = 0; j < 4; j++) {
                int row = wn + 16 * j + lrow;
                bf[j] = *(const short8*)&Bs[row * BK + (((ks << 2) + quad + row) & 7) * 8];
            }
#pragma unroll
            for (int i = 0; i < 2; i++)
#pragma unroll
                for (int j = 0; j < 4; j++)
                    acc[i][j] = __builtin_amdgcn_mfma_f32_16x16x32_bf16(af[i], bf[j], acc[i][j], 0, 0, 0);
        }
        __syncthreads();
    }

    // epilogue: bias + gate-scale -> LDS repack -> coalesced stores
#pragma unroll
    for (int j = 0; j < 4; j++) {
        int col = wn + 16 * j + lrow;
        float b2v = b2[e * DD + n0 + col];
#pragma unroll
        for (int i = 0; i < 2; i++) {
#pragma unroll
            for (int r = 0; r < 4; r++) {
                int m = wm + 16 * i + quad * 4 + r;
                float v = (acc[i][j][r] + b2v) * gts[m];
                smem[m * RP + col] = f2bf(v);
            }
        }
    }
    __syncthreads();
    {
        int row = t >> 2, q = t & 3;   // 512 thr: 128 rows x 4 chunks of 32 elems
        if (m0 + row < cnt) {
            unsigned short* dst = ybuf + (size_t)(base + m0 + row) * DD + n0 + q * 32;
            const unsigned short* src = smem + row * RP + q * 32;
#pragma unroll
            for (int it = 0; it < 4; it++)
                *(uint4*)(dst + it * 8) = *(const uint4*)(src + it * 8);
        }
    }
}

// ---------------- combine: out[n] = ybuf[slot(n,0)] + ybuf[slot(n,1)] ----------------
__global__ void k_combine(const unsigned short* __restrict__ ybuf, const int* __restrict__ slotof,
                          float* __restrict__ out) {
    int n = blockIdx.x * 2 + (threadIdx.x >> 7);
    int c = (threadIdx.x & 127) * 4;
    int sA = slotof[2 * n], sB = slotof[2 * n + 1];
    ushort4 a = *(const ushort4*)(ybuf + (size_t)sA * DD + c);
    ushort4 b = *(const ushort4*)(ybuf + (size_t)sB * DD + c);
    float4 o;
    o.x = bf2f(a.x) + bf2f(b.x);
    o.y = bf2f(a.y) + bf2f(b.y);
    o.z = bf2f(a.z) + bf2f(b.z);
    o.w = bf2f(a.w) + bf2f(b.w);
    *(float4*)(out + (size_t)n * DD + c) = o;
}

extern "C" void kernel_launch(void* const* d_in, const int* in_sizes, int n_in,
                              void* d_out, int out_size, void* d_ws, size_t ws_size,
                              hipStream_t stream) {
    const float* h  = (const float*)d_in[0];
    const float* wg = (const float*)d_in[1];
    const float* w1 = (const float*)d_in[2];
    const float* b1 = (const float*)d_in[3];
    const float* w2 = (const float*)d_in[4];
    const float* b2 = (const float*)d_in[5];
    float* out = (float*)d_out;

    char* ws = (char*)d_ws;
    size_t off = 0;
    auto alloc = [&](size_t bytes) -> void* {
        void* p = ws + off;
        off += (bytes + 255) & ~(size_t)255;
        return p;
    };
    unsigned short* hb  = (unsigned short*)alloc((size_t)NT * DD * 2);        // dead after ffn1
    unsigned short* w1t = (unsigned short*)alloc((size_t)NE * HH * DD * 2);   // dead after ffn1
    unsigned short* w2t = (unsigned short*)alloc((size_t)NE * DD * HH * 2);
    int*   sel    = (int*)alloc((size_t)NT * 2 * 4);
    float* gv     = (float*)alloc((size_t)NT * 2 * 4);
    int*   ctl    = (int*)alloc(256);
    int*   rtok   = (int*)alloc((size_t)NT * 2 * 4);
    float* rgte   = (float*)alloc((size_t)NT * 2 * 4);
    int*   slotof = (int*)alloc((size_t)NT * 2 * 4);
    unsigned short* mid = (unsigned short*)alloc((size_t)NT * 2 * HH * 2);
    // ybuf [NT*2][DD] bf16 (16.7 MB) aliases hb+w1t (16.7 MB), both dead before ffn2 runs
    unsigned short* ybuf = (unsigned short*)ws;

    k_transpose_cast<<<dim3(HH / 32, DD / 32, 2 * NE), 256, 0, stream>>>(w1, w1t, w2, w2t);
    k_gate<<<dim3(NT / 4), 256, 0, stream>>>(h, wg, sel, gv, hb);
    k_scan<<<1, 1024, 0, stream>>>(sel, gv, ctl, rtok, rgte, slotof);
    k_ffn1<<<dim3(HH / 128, NT / 128, NE), 256, 0, stream>>>(hb, w1t, b1, ctl, rtok, mid);
    k_ffn2<<<dim3(DD / 128, NT / 128, NE), 512, 0, stream>>>(mid, w2t, b2, ctl, rgte, ybuf);
    k_combine<<<dim3(NT / 2), 256, 0, stream>>>(ybuf, slotof, out);
}

// Round 5
// 272.665 us; speedup vs baseline: 1.1760x; 1.1760x over previous
//
#include <hip/hip_runtime.h>
#include <hip/hip_bf16.h>
#include <cstdint>
#include <cstddef>

// Problem constants
#define NT 8192
#define DD 512
#define HH 2048
#define NE 4
#define BK 64          // K-tile (bf16 elems); 8 chunks of 16B per row
#define RP 136         // repack LDS stride (elems) — breaks bank alignment
#define SMEM_ELEMS 17408  // max(staging 2*128*64=16384, repack 128*136=17408)
#define MAXTILES 131   // sum_e ceil(cnt_e/128) <= 128 + (NE-1)

typedef short short8 __attribute__((ext_vector_type(8)));
typedef float floatx4 __attribute__((ext_vector_type(4)));

static __device__ __forceinline__ unsigned short f2bf(float f) {
    union { float f; uint32_t u; } v; v.f = f;
    uint32_t u = v.u;
    u += 0x7FFFu + ((u >> 16) & 1u);   // round-to-nearest-even
    return (unsigned short)(u >> 16);
}
static __device__ __forceinline__ float bf2f(unsigned short u) {
    union { uint32_t u; float f; } v; v.u = ((uint32_t)u) << 16; return v.f;
}

// async global->LDS, 16B per lane. LDS dest = wave-uniform base + lane*16.
static __device__ __forceinline__ void gld_lds16(const unsigned short* g, unsigned short* l) {
    __builtin_amdgcn_global_load_lds(
        (const __attribute__((address_space(1))) void*)g,
        (__attribute__((address_space(3))) void*)l, 16, 0, 0);
}

// ------------- merged batched transpose + cast (w1 and w2 in one launch) -------------
__global__ void k_transpose_cast(const float* __restrict__ w1, unsigned short* __restrict__ w1t,
                                 const float* __restrict__ w2, unsigned short* __restrict__ w2t) {
    int z = blockIdx.z;
    const float* in; unsigned short* out; int R, C, r0, c0;
    if (z < 4) {
        in = w1 + (size_t)z * DD * HH; out = w1t + (size_t)z * DD * HH;
        R = DD; C = HH; r0 = blockIdx.y * 32; c0 = blockIdx.x * 32;
    } else {
        in = w2 + (size_t)(z - 4) * HH * DD; out = w2t + (size_t)(z - 4) * HH * DD;
        R = HH; C = DD; r0 = blockIdx.x * 32; c0 = blockIdx.y * 32;
    }
    __shared__ float tile[32][33];
    int tx = threadIdx.x & 31, ty = threadIdx.x >> 5;
#pragma unroll
    for (int it = 0; it < 4; it++) {
        int r = ty + it * 8;
        tile[r][tx] = in[(size_t)(r0 + r) * C + c0 + tx];
    }
    __syncthreads();
#pragma unroll
    for (int it = 0; it < 4; it++) {
        int r = ty + it * 8;
        out[(size_t)(c0 + r) * R + r0 + tx] = f2bf(tile[tx][r]);
    }
}

// ------- gating (fp32 logits, exact top-2, softmax over top-2) + fused h->bf16 cast -------
__global__ void k_gate(const float* __restrict__ h, const float* __restrict__ wg,
                       int* __restrict__ sel, float* __restrict__ gv,
                       unsigned short* __restrict__ hb) {
    int wid = threadIdx.x >> 6, lane = threadIdx.x & 63;
    int n = blockIdx.x * 4 + wid;
    const float* hr = h + (size_t)n * DD;
    int d0 = lane * 8;
    float hv[8];
    *(float4*)(hv)     = *(const float4*)(hr + d0);
    *(float4*)(hv + 4) = *(const float4*)(hr + d0 + 4);
    unsigned short tmp[8];
#pragma unroll
    for (int j = 0; j < 8; j++) tmp[j] = f2bf(hv[j]);
    *(uint4*)(hb + (size_t)n * DD + d0) = *(const uint4*)tmp;

    float a0 = 0.f, a1 = 0.f, a2 = 0.f, a3 = 0.f;
#pragma unroll
    for (int j = 0; j < 8; j++) {
        float4 w = *(const float4*)(wg + (size_t)(d0 + j) * 4);
        a0 += hv[j] * w.x; a1 += hv[j] * w.y; a2 += hv[j] * w.z; a3 += hv[j] * w.w;
    }
#pragma unroll
    for (int off = 32; off; off >>= 1) {
        a0 += __shfl_xor(a0, off);
        a1 += __shfl_xor(a1, off);
        a2 += __shfl_xor(a2, off);
        a3 += __shfl_xor(a3, off);
    }
    if (lane == 0) {
        float v[4] = {a0, a1, a2, a3};
        int e0 = 0; float b = v[0];
#pragma unroll
        for (int e = 1; e < 4; e++) if (v[e] > b) { b = v[e]; e0 = e; }
        int e1 = -1; float b2 = -1e30f;
#pragma unroll
        for (int e = 0; e < 4; e++) if (e != e0 && v[e] > b2) { b2 = v[e]; e1 = e; }
        float x = expf(b2 - b);
        float s = 1.f + x;
        sel[2 * n] = e0; sel[2 * n + 1] = e1;
        gv[2 * n] = 1.f / s; gv[2 * n + 1] = x / s;
    }
}

// ---------------- single-block scan (1024 thr): counts -> offsets -> slots -> tile table ----------------
// ctl: [8..11]=expert base, [12]=total, [13]=numTiles
// tiles[i] = (expert << 16) | m0
__global__ __launch_bounds__(1024) void k_scan(const int* __restrict__ sel, const float* __restrict__ gv,
                                               int* __restrict__ ctl, int* __restrict__ rtok,
                                               float* __restrict__ rgte, int* __restrict__ slotof,
                                               int* __restrict__ tiles) {
    __shared__ int cnt[4][1024];
    __shared__ int ebase[4];
    int t = threadIdx.x;
    int c[4] = {0, 0, 0, 0};
    int selloc[16];
    const int4* s4 = (const int4*)sel;
#pragma unroll
    for (int i = 0; i < 4; i++) {
        int4 v = s4[t * 4 + i];
        selloc[i * 4 + 0] = v.x; c[v.x]++;
        selloc[i * 4 + 1] = v.y; c[v.y]++;
        selloc[i * 4 + 2] = v.z; c[v.z]++;
        selloc[i * 4 + 3] = v.w; c[v.w]++;
    }
#pragma unroll
    for (int e = 0; e < 4; e++) cnt[e][t] = c[e];
    __syncthreads();
    for (int step = 1; step < 1024; step <<= 1) {
        int v[4];
#pragma unroll
        for (int e = 0; e < 4; e++) v[e] = (t >= step) ? cnt[e][t - step] : 0;
        __syncthreads();
#pragma unroll
        for (int e = 0; e < 4; e++) cnt[e][t] += v[e];
        __syncthreads();
    }
    if (t == 0) {
        int o = 0, nt = 0;
#pragma unroll
        for (int e = 0; e < 4; e++) {
            int ce = cnt[e][1023];
            ebase[e] = o; ctl[8 + e] = o; o += ce;
            for (int m0 = 0; m0 < ce; m0 += 128) tiles[nt++] = (e << 16) | m0;
        }
        ctl[12] = o;
        ctl[13] = nt;
    }
    __syncthreads();
    int pos[4];
#pragma unroll
    for (int e = 0; e < 4; e++) pos[e] = ebase[e] + cnt[e][t] - c[e];  // exclusive prefix
#pragma unroll
    for (int i = 0; i < 16; i++) {
        int idx = t * 16 + i;          // = 2*n + k
        int e = selloc[i];
        int s = pos[e]++;
        rtok[s] = idx >> 1;
        rgte[s] = gv[idx];
        slotof[idx] = s;
    }
}

// ---------------- grouped GEMM 1: mid = relu(gather(h) @ w1[e] + b1[e]) ----------------
__global__ __launch_bounds__(256) void k_ffn1(
    const unsigned short* __restrict__ hb, const unsigned short* __restrict__ w1t,
    const float* __restrict__ b1, const int* __restrict__ ctl, const int* __restrict__ tiles,
    const int* __restrict__ rtok, unsigned short* __restrict__ mid) {
    if ((int)blockIdx.y >= ctl[13]) return;
    int tv = tiles[blockIdx.y];
    int e = tv >> 16, m0 = tv & 0xFFFF;
    int base = ctl[8 + e];
    int cnt = ctl[9 + e] - base;
    int n0 = blockIdx.x * 128;

    __shared__ unsigned short smem[SMEM_ELEMS];
    __shared__ int toks[128];
    unsigned short* As = smem;          // [128][64], swizzled chunks
    unsigned short* Bs = smem + 8192;

    int t = threadIdx.x;
    if (t < 128) {
        int r = m0 + t; if (r >= cnt) r = cnt - 1;
        toks[t] = rtok[base + r];
    }
    __syncthreads();

    const unsigned short* wB = w1t + (size_t)e * HH * DD;
    int wid = t >> 6, lane = t & 63;
    int wm = (wid & 1) * 64, wn = (wid >> 1) * 64;
    int lrow = lane & 15, quad = lane >> 4;

    // staging: wave stages 8 rows (128B each) per call, 4 calls per matrix.
    // swizzle: LDS slot (row, p) holds global chunk (p - row) & 7.
    const unsigned short* gA[4]; const unsigned short* gB[4];
    unsigned short* lA[4]; unsigned short* lB[4];
    int srow8 = lane >> 3, sch = lane & 7;
#pragma unroll
    for (int c = 0; c < 4; c++) {
        int row = wid * 32 + c * 8 + srow8;
        int cg = (sch - row) & 7;
        gA[c] = hb + (size_t)toks[row] * DD + cg * 8;
        gB[c] = wB + (size_t)(n0 + row) * DD + cg * 8;
        lA[c] = As + row * BK + sch * 8;
        lB[c] = Bs + row * BK + sch * 8;
    }

    floatx4 acc[4][4];
#pragma unroll
    for (int i = 0; i < 4; i++)
#pragma unroll
        for (int j = 0; j < 4; j++) acc[i][j] = (floatx4)0.f;

    for (int kk = 0; kk < DD; kk += BK) {
#pragma unroll
        for (int c = 0; c < 4; c++) {
            gld_lds16(gA[c] + kk, lA[c]);
            gld_lds16(gB[c] + kk, lB[c]);
        }
        __syncthreads();
#pragma unroll
        for (int ks = 0; ks < 2; ks++) {
            short8 af[4], bf[4];
#pragma unroll
            for (int i = 0; i < 4; i++) {
                int row = wm + 16 * i + lrow;
                af[i] = *(const short8*)&As[row * BK + (((ks << 2) + quad + row) & 7) * 8];
            }
#pragma unroll
            for (int j = 0; j < 4; j++) {
                int row = wn + 16 * j + lrow;
                bf[j] = *(const short8*)&Bs[row * BK + (((ks << 2) + quad + row) & 7) * 8];
            }
#pragma unroll
            for (int i = 0; i < 4; i++)
#pragma unroll
                for (int j = 0; j < 4; j++)
                    acc[i][j] = __builtin_amdgcn_mfma_f32_16x16x32_bf16(af[i], bf[j], acc[i][j], 0, 0, 0);
        }
        __syncthreads();
    }

    // epilogue: bias + relu -> LDS repack -> coalesced dwordx4 stores
#pragma unroll
    for (int j = 0; j < 4; j++) {
        int col = wn + 16 * j + lrow;
        float bias = b1[e * HH + n0 + col];
#pragma unroll
        for (int i = 0; i < 4; i++) {
#pragma unroll
            for (int r = 0; r < 4; r++) {
                int m = wm + 16 * i + quad * 4 + r;
                float v = acc[i][j][r] + bias;
                v = v > 0.f ? v : 0.f;
                smem[m * RP + col] = f2bf(v);
            }
        }
    }
    __syncthreads();
    {
        int row = t >> 1, half = t & 1;
        if (m0 + row < cnt) {
            unsigned short* dst = mid + (size_t)(base + m0 + row) * HH + n0 + half * 64;
            const unsigned short* src = smem + row * RP + half * 64;
#pragma unroll
            for (int it = 0; it < 8; it++)
                *(uint4*)(dst + it * 8) = *(const uint4*)(src + it * 8);
        }
    }
}

// ---------------- grouped GEMM 2 (512 thr, 8 waves): ybuf[slot] = gate * (mid @ w2[e] + b2[e]) ----------------
__global__ __launch_bounds__(512) void k_ffn2(
    const unsigned short* __restrict__ mid, const unsigned short* __restrict__ w2t,
    const float* __restrict__ b2, const int* __restrict__ ctl, const int* __restrict__ tiles,
    const float* __restrict__ rgte, unsigned short* __restrict__ ybuf) {
    if ((int)blockIdx.y >= ctl[13]) return;
    int tv = tiles[blockIdx.y];
    int e = tv >> 16, m0 = tv & 0xFFFF;
    int base = ctl[8 + e];
    int cnt = ctl[9 + e] - base;
    int n0 = blockIdx.x * 128;

    __shared__ unsigned short smem[SMEM_ELEMS];
    __shared__ float gts[128];
    unsigned short* As = smem;
    unsigned short* Bs = smem + 8192;

    int t = threadIdx.x;
    if (t < 128) {
        int r = m0 + t; if (r >= cnt) r = cnt - 1;
        gts[t] = rgte[base + r];
    }
    __syncthreads();

    const unsigned short* wB = w2t + (size_t)e * DD * HH;
    int w = t >> 6, lane = t & 63;
    // wave tile: 32 (m) x 64 (n); 4x2 wave grid covers 128x128
    int wm = (w & 3) * 32, wn = (w >> 2) * 64;
    int lrow = lane & 15, quad = lane >> 4;

    // staging: waves 0-3 stage A (128 rows), waves 4-7 stage B (128 rows); 4 calls each
    const unsigned short* g[4]; unsigned short* l[4];
    int srow8 = lane >> 3, sch = lane & 7;
    int wrow0 = (w & 3) * 32;
    bool isA = w < 4;
#pragma unroll
    for (int c = 0; c < 4; c++) {
        int row = wrow0 + c * 8 + srow8;
        int cg = (sch - row) & 7;
        if (isA) {
            int ra = m0 + row; if (ra >= cnt) ra = cnt - 1;
            g[c] = mid + (size_t)(base + ra) * HH + cg * 8;
            l[c] = As + row * BK + sch * 8;
        } else {
            g[c] = wB + (size_t)(n0 + row) * HH + cg * 8;
            l[c] = Bs + row * BK + sch * 8;
        }
    }

    floatx4 acc[2][4];
#pragma unroll
    for (int i = 0; i < 2; i++)
#pragma unroll
        for (int j = 0; j < 4; j++) acc[i][j] = (floatx4)0.f;

    for (int kk = 0; kk < HH; kk += BK) {
#pragma unroll
        for (int c = 0; c < 4; c++) gld_lds16(g[c] + kk, l[c]);
        __syncthreads();
#pragma unroll
        for (int ks = 0; ks < 2; ks++) {
            short8 af[2], bf[4];
#pragma unroll
            for (int i = 0; i < 2; i++) {
                int row = wm + 16 * i + lrow;
                af[i] = *(const short8*)&As[row * BK + (((ks << 2) + quad + row) & 7) * 8];
            }
#pragma unroll
            for (int j = 0; j < 4; j++) {
                int row = wn + 16 * j + lrow;
                bf[j] = *(const short8*)&Bs[row * BK + (((ks << 2) + quad + row) & 7) * 8];
            }
#pragma unroll
            for (int i = 0; i < 2; i++)
#pragma unroll
                for (int j = 0; j < 4; j++)
                    acc[i][j] = __builtin_amdgcn_mfma_f32_16x16x32_bf16(af[i], bf[j], acc[i][j], 0, 0, 0);
        }
        __syncthreads();
    }

    // epilogue: bias + gate-scale -> LDS repack -> coalesced stores
#pragma unroll
    for (int j = 0; j < 4; j++) {
        int col = wn + 16 * j + lrow;
        float b2v = b2[e * DD + n0 + col];
#pragma unroll
        for (int i = 0; i < 2; i++) {
#pragma unroll
            for (int r = 0; r < 4; r++) {
                int m = wm + 16 * i + quad * 4 + r;
                float v = (acc[i][j][r] + b2v) * gts[m];
                smem[m * RP + col] = f2bf(v);
            }
        }
    }
    __syncthreads();
    {
        int row = t >> 2, q = t & 3;   // 512 thr: 128 rows x 4 chunks of 32 elems
        if (m0 + row < cnt) {
            unsigned short* dst = ybuf + (size_t)(base + m0 + row) * DD + n0 + q * 32;
            const unsigned short* src = smem + row * RP + q * 32;
#pragma unroll
            for (int it = 0; it < 4; it++)
                *(uint4*)(dst + it * 8) = *(const uint4*)(src + it * 8);
        }
    }
}

// ---------------- combine: out[n] = ybuf[slot(n,0)] + ybuf[slot(n,1)] ----------------
__global__ void k_combine(const unsigned short* __restrict__ ybuf, const int* __restrict__ slotof,
                          float* __restrict__ out) {
    int n = blockIdx.x * 2 + (threadIdx.x >> 7);
    int c = (threadIdx.x & 127) * 4;
    int sA = slotof[2 * n], sB = slotof[2 * n + 1];
    ushort4 a = *(const ushort4*)(ybuf + (size_t)sA * DD + c);
    ushort4 b = *(const ushort4*)(ybuf + (size_t)sB * DD + c);
    float4 o;
    o.x = bf2f(a.x) + bf2f(b.x);
    o.y = bf2f(a.y) + bf2f(b.y);
    o.z = bf2f(a.z) + bf2f(b.z);
    o.w = bf2f(a.w) + bf2f(b.w);
    *(float4*)(out + (size_t)n * DD + c) = o;
}

extern "C" void kernel_launch(void* const* d_in, const int* in_sizes, int n_in,
                              void* d_out, int out_size, void* d_ws, size_t ws_size,
                              hipStream_t stream) {
    const float* h  = (const float*)d_in[0];
    const float* wg = (const float*)d_in[1];
    const float* w1 = (const float*)d_in[2];
    const float* b1 = (const float*)d_in[3];
    const float* w2 = (const float*)d_in[4];
    const float* b2 = (const float*)d_in[5];
    float* out = (float*)d_out;

    char* ws = (char*)d_ws;
    size_t off = 0;
    auto alloc = [&](size_t bytes) -> void* {
        void* p = ws + off;
        off += (bytes + 255) & ~(size_t)255;
        return p;
    };
    unsigned short* hb  = (unsigned short*)alloc((size_t)NT * DD * 2);        // dead after ffn1
    unsigned short* w1t = (unsigned short*)alloc((size_t)NE * HH * DD * 2);   // dead after ffn1
    unsigned short* w2t = (unsigned short*)alloc((size_t)NE * DD * HH * 2);
    int*   sel    = (int*)alloc((size_t)NT * 2 * 4);
    float* gv     = (float*)alloc((size_t)NT * 2 * 4);
    int*   ctl    = (int*)alloc(256);
    int*   tiles  = (int*)alloc(1024);
    int*   rtok   = (int*)alloc((size_t)NT * 2 * 4);
    float* rgte   = (float*)alloc((size_t)NT * 2 * 4);
    int*   slotof = (int*)alloc((size_t)NT * 2 * 4);
    unsigned short* mid = (unsigned short*)alloc((size_t)NT * 2 * HH * 2);
    // ybuf [NT*2][DD] bf16 (16.7 MB) aliases hb+w1t (16.7 MB), both dead before ffn2 runs
    unsigned short* ybuf = (unsigned short*)ws;

    k_transpose_cast<<<dim3(HH / 32, DD / 32, 2 * NE), 256, 0, stream>>>(w1, w1t, w2, w2t);
    k_gate<<<dim3(NT / 4), 256, 0, stream>>>(h, wg, sel, gv, hb);
    k_scan<<<1, 1024, 0, stream>>>(sel, gv, ctl, rtok, rgte, slotof, tiles);
    k_ffn1<<<dim3(HH / 128, MAXTILES), 256, 0, stream>>>(hb, w1t, b1, ctl, tiles, rtok, mid);
    k_ffn2<<<dim3(DD / 128, MAXTILES), 512, 0, stream>>>(mid, w2t, b2, ctl, tiles, rgte, ybuf);
    k_combine<<<dim3(NT / 2), 256, 0, stream>>>(ybuf, slotof, out);
}